// Round 8
// baseline (192.534 us; speedup 1.0000x reference)
//
#include <hip/hip_runtime.h>
#include <hip/hip_bf16.h>

constexpr int B = 256, S = 1024, T = 64;
constexpr float LOG2E = 1.4426950408889634f;
constexpr float LN2   = 0.6931471805599453f;

typedef _Float16 h2 __attribute__((ext_vector_type(2)));

static __device__ __forceinline__ float dot2f(unsigned int abits, h2 b, float c) {
    return __builtin_amdgcn_fdot2(__builtin_bit_cast(h2, abits), b, c, false);
}
static __device__ __forceinline__ unsigned int pack2(float lo, float hi) {
    return __builtin_bit_cast(unsigned int, __builtin_amdgcn_cvt_pkrtz(lo, hi));
}

// One wave per chain; the wave runs BOTH the forward (a) and backward (u)
// recursions interleaved — chain B's instructions fill chain A's latency
// stalls. q-broadcast via LDS uniform-address ds_read_b128 (no readlanes,
// no barriers: single wave, LDS ops are in-order; parity double-buffer).
__global__ __launch_bounds__(64, 1) void crf_pair(
        const float* __restrict__ emis, const int* __restrict__ tags,
        const float* __restrict__ U,    const float* __restrict__ bs,
        const float* __restrict__ be,   float* __restrict__ nll) {
    __shared__ __align__(16) _Float16 qsh[2][2][T];   // [parity][dir][tag] = 512 B
    const int chain = blockIdx.x;
    const int j = threadIdx.x;
    const float* eb = emis + (size_t)chain * (S * T);
    const int*   tb = tags + (size_t)chain * S;

    // W fragments: fwd (A) needs columns of W=e^U, bwd (B) needs rows.
    h2 WA[32], WB[32];
#pragma unroll
    for (int m = 0; m < 32; ++m) {
        WA[m] = __builtin_bit_cast(h2, pack2(
            __builtin_amdgcn_exp2f(U[(2 * m)     * T + j] * LOG2E),
            __builtin_amdgcn_exp2f(U[(2 * m + 1) * T + j] * LOG2E)));
        WB[m] = __builtin_bit_cast(h2, pack2(
            __builtin_amdgcn_exp2f(U[j * T + 2 * m]     * LOG2E),
            __builtin_amdgcn_exp2f(U[j * T + 2 * m + 1] * LOG2E)));
    }

    // ---- path energy (exact, f32, whole chain) ----
    float pe = 0.f;
#pragma unroll
    for (int sc = 0; sc < 16; ++sc) {
        int s  = sc * 64 + j;
        int tg = tb[s];
        float e = eb[(size_t)s * T + tg];
        if (s == 0)     e += bs[tg];
        if (s == S - 1) e += be[tg];
        pe += e;
        if (s < S - 1)  pe += U[tg * T + tb[s + 1]];
    }
#pragma unroll
    for (int m = 1; m < 64; m <<= 1) pe += __shfl_xor(pe, m, 64);

    // ---- inits: A = a_0 (fwd), B = u_1023 = e^{x_1023+be} (bwd) ----
    float aA = (eb[j] + bs[j]) * LOG2E;
    float MA = aA;
#pragma unroll
    for (int m = 1; m < 64; m <<= 1) MA = fmaxf(MA, __shfl_xor(MA, m, 64));
    float pA = __builtin_amdgcn_exp2f(aA - MA);
    int ciA = 0; const float cfA = MA;

    float aB = (eb[(size_t)(S - 1) * T + j] + be[j]) * LOG2E;
    float MB = aB;
#pragma unroll
    for (int m = 1; m < 64; m <<= 1) MB = fmaxf(MB, __shfl_xor(MB, m, 64));
    float pB = __builtin_amdgcn_exp2f(aB - MB);
    int ciB = 0; const float cfB = MB;

    auto renormA = [&](float ss) -> float {
        unsigned int sb = __builtin_amdgcn_readfirstlane(__float_as_uint(ss));
        int e = (int)((sb >> 23) & 0xFF);
        ciA += e - 127;
        return ss * __uint_as_float((unsigned int)(254 - e) << 23);
    };
    auto renormB = [&](float ss) -> float {
        unsigned int sb = __builtin_amdgcn_readfirstlane(__float_as_uint(ss));
        int e = (int)((sb >> 23) & 0xFF);
        ciB += e - 127;
        return ss * __uint_as_float((unsigned int)(254 - e) << 23);
    };

    // one interleaved double-step (par is compile-time under unroll)
    auto dstep = [&](float xA, float xB, int par) {
        float exA = __builtin_amdgcn_exp2f(xA * LOG2E);
        float exB = __builtin_amdgcn_exp2f(xB * LOG2E);
        qsh[par][0][j] = (_Float16)pA;
        qsh[par][1][j] = (_Float16)pB;
        const uint4* qa = (const uint4*)qsh[par][0];
        const uint4* qb = (const uint4*)qsh[par][1];
        float a0 = 0.f, a1 = 0.f, a2 = 0.f, a3 = 0.f;
        float b0 = 0.f, b1 = 0.f, b2 = 0.f, b3 = 0.f;
#pragma unroll
        for (int g = 0; g < 8; ++g) {
            uint4 va = qa[g], vb = qb[g];            // uniform-address broadcast
            a0 = dot2f(va.x, WA[4 * g + 0], a0);
            a1 = dot2f(va.y, WA[4 * g + 1], a1);
            a2 = dot2f(va.z, WA[4 * g + 2], a2);
            a3 = dot2f(va.w, WA[4 * g + 3], a3);
            b0 = dot2f(vb.x, WB[4 * g + 0], b0);
            b1 = dot2f(vb.y, WB[4 * g + 1], b1);
            b2 = dot2f(vb.z, WB[4 * g + 2], b2);
            b3 = dot2f(vb.w, WB[4 * g + 3], b3);
        }
        pA = renormA((a0 + a1) + (a2 + a3)) * exA;
        pB = renormB((b0 + b1) + (b2 + b3)) * exB;
    };
    // fwd-only step for the unpaired final slot
    auto fstep = [&](float xA, int par) {
        float exA = __builtin_amdgcn_exp2f(xA * LOG2E);
        qsh[par][0][j] = (_Float16)pA;
        const uint4* qa = (const uint4*)qsh[par][0];
        float a0 = 0.f, a1 = 0.f, a2 = 0.f, a3 = 0.f;
#pragma unroll
        for (int g = 0; g < 8; ++g) {
            uint4 va = qa[g];
            a0 = dot2f(va.x, WA[4 * g + 0], a0);
            a1 = dot2f(va.y, WA[4 * g + 1], a1);
            a2 = dot2f(va.z, WA[4 * g + 2], a2);
            a3 = dot2f(va.w, WA[4 * g + 3], a3);
        }
        pA = renormA((a0 + a1) + (a2 + a3)) * exA;
    };

    // slot u: fwd t=1+u (u=0..510; u=511 -> plain matvec, x=0)
    //         bwd t=1022-u (u=0..510; slot 511 unused)
    auto xldA = [&](int u) {
        int uu = u < 510 ? u : 510;
        float v = eb[(size_t)(1 + uu) * T + j];
        return u < 511 ? v : 0.0f;
    };
    auto xldB = [&](int u) {
        int uu = u < 510 ? u : 510;
        return eb[(size_t)(1022 - uu) * T + j];
    };

    // ---- 512 slots, 8-deep ping-pong prefetch for both chains ----
    float xaA[8], xbA[8], xaB[8], xbB[8];
#pragma unroll
    for (int u = 0; u < 8; ++u) { xaA[u] = xldA(u); xaB[u] = xldB(u); }
    int u0 = 0;
    for (int k = 0; k < 31; ++k) {                  // slots 0..495
#pragma unroll
        for (int v = 0; v < 8; ++v) { xbA[v] = xldA(u0 + 8 + v); xbB[v] = xldB(u0 + 8 + v); }
#pragma unroll
        for (int v = 0; v < 8; ++v) dstep(xaA[v], xaB[v], v & 1);
#pragma unroll
        for (int v = 0; v < 8; ++v) { xaA[v] = xldA(u0 + 16 + v); xaB[v] = xldB(u0 + 16 + v); }
#pragma unroll
        for (int v = 0; v < 8; ++v) dstep(xbA[v], xbB[v], v & 1);
        u0 += 16;
    }
    // u0 = 496; xa* hold slots 496..503
#pragma unroll
    for (int v = 0; v < 8; ++v) { xbA[v] = xldA(504 + v); xbB[v] = xldB(504 + v); }
#pragma unroll
    for (int v = 0; v < 8; ++v) dstep(xaA[v], xaB[v], v & 1);
#pragma unroll
    for (int v = 0; v < 7; ++v) dstep(xbA[v], xbB[v], v & 1);
    fstep(xbA[7], 1);                               // slot 511, x = 0

    // ---- combine: free = ln2*(log2(sum_j pA_j pB_j) + C_A + C_B) ----
    float v = pA * pB;
#pragma unroll
    for (int m = 1; m < 64; m <<= 1) v += __shfl_xor(v, m, 64);
    if (j == 0) {
        float free_e = LN2 * (__builtin_amdgcn_logf(v)
                              + cfA + (float)ciA + cfB + (float)ciB);
        nll[chain] = free_e - pe;
    }
}

__global__ __launch_bounds__(256, 1) void crf_reduce(const float* __restrict__ nll,
                                                     float* __restrict__ out) {
    float v = nll[threadIdx.x];
#pragma unroll
    for (int m = 1; m < 64; m <<= 1) v += __shfl_xor(v, m, 64);
    __shared__ float acc[4];
    if ((threadIdx.x & 63) == 0) acc[threadIdx.x >> 6] = v;
    __syncthreads();
    if (threadIdx.x == 0) out[0] = (acc[0] + acc[1] + acc[2] + acc[3]) * (1.0f / B);
}

extern "C" void kernel_launch(void* const* d_in, const int* in_sizes, int n_in,
                              void* d_out, int out_size, void* d_ws, size_t ws_size,
                              hipStream_t stream) {
    const float* emis = (const float*)d_in[0];
    const int*   tags = (const int*)d_in[1];
    const float* U    = (const float*)d_in[2];
    const float* bs   = (const float*)d_in[3];
    const float* be   = (const float*)d_in[4];
    float* nll = (float*)d_ws;

    crf_pair<<<dim3(B), dim3(64), 0, stream>>>(emis, tags, U, bs, be, nll);
    crf_reduce<<<dim3(1), dim3(256), 0, stream>>>(nll, (float*)d_out);
}

// Round 10
// 187.207 us; speedup vs baseline: 1.0285x; 1.0285x over previous
//
#include <hip/hip_runtime.h>
#include <hip/hip_bf16.h>

constexpr int B = 256, S = 1024, T = 64;
constexpr float LOG2E = 1.4426950408889634f;
constexpr float LN2   = 0.6931471805599453f;

typedef _Float16 h2 __attribute__((ext_vector_type(2)));

static __device__ __forceinline__ h2 pk(float lo, float hi) {
    return __builtin_bit_cast(h2, __builtin_amdgcn_cvt_pkrtz(lo, hi));
}
static __device__ __forceinline__ h2 bcast(unsigned int bits, int lane) {
    return __builtin_bit_cast(h2, __builtin_amdgcn_readlane(bits, lane));
}

// One wave per chain. Lane j owns tag j. The f16x2 halves of the state hold
// the forward (lo) and backward (hi) recursions: one readlane broadcasts both,
// one v_pk_fma_f16 advances both. Both halves use the SAME step form:
//   p <- renorm(Wfrag-matvec(p)) * e^{x_slot}
// fwd: alpha_t = D_t W^T alpha_{t-1}; bwd: u_t = D_t W u_{t+1} (u_1023 = D_1023*1).
// Meet: free = ln( u_512^T (W^T a_511) ) + offsets.
__global__ __launch_bounds__(64, 1) void crf_pair(
        const float* __restrict__ emis, const int* __restrict__ tags,
        const float* __restrict__ U,    const float* __restrict__ bs,
        const float* __restrict__ be,   float* __restrict__ nll) {
    const int chain = blockIdx.x;
    const int j = threadIdx.x;
    const float* eb = emis + (size_t)chain * (S * T);
    const int*   tb = tags + (size_t)chain * S;

    // Wpk[i] = ( W[i][j], W[j][i] ) : fwd needs columns of W=e^U, bwd needs rows
    h2 Wpk[64];
#pragma unroll
    for (int i = 0; i < 64; ++i) {
        float wf = __builtin_amdgcn_exp2f(U[i * T + j] * LOG2E);
        float wb = __builtin_amdgcn_exp2f(U[j * T + i] * LOG2E);
        Wpk[i] = pk(wf, wb);
    }

    // ---- path energy (exact, f32, whole chain) ----
    float pe = 0.f;
#pragma unroll
    for (int sc = 0; sc < 16; ++sc) {
        int s  = sc * 64 + j;
        int tg = tb[s];
        float e = eb[(size_t)s * T + tg];
        if (s == 0)     e += bs[tg];
        if (s == S - 1) e += be[tg];
        pe += e;
        if (s < S - 1)  pe += U[tg * T + tb[s + 1]];
    }
#pragma unroll
    for (int m = 1; m < 64; m <<= 1) pe += __shfl_xor(pe, m, 64);

    // ---- inits (log2 domain) ----
    float aA = (eb[j] + bs[j]) * LOG2E;
    float MA = aA;
#pragma unroll
    for (int m = 1; m < 64; m <<= 1) MA = fmaxf(MA, __shfl_xor(MA, m, 64));
    float pA = __builtin_amdgcn_exp2f(aA - MA);
    int ciA = 0; const float cfA = MA;

    float aB = (eb[(size_t)(S - 1) * T + j] + be[j]) * LOG2E;
    float MB = aB;
#pragma unroll
    for (int m = 1; m < 64; m <<= 1) MB = fmaxf(MB, __shfl_xor(MB, m, 64));
    float pB = __builtin_amdgcn_exp2f(aB - MB);
    int ciB = 0; const float cfB = MB;

    h2 ppk = pk(pA, pB);

    // one packed double-step: both chains mix-then-scale
    auto dstep = [&](float xA, float xB) {
        float exA = __builtin_amdgcn_exp2f(xA * LOG2E);    // off critical chain
        float exB = __builtin_amdgcn_exp2f(xB * LOG2E);
        unsigned int qb = __builtin_bit_cast(unsigned int, ppk);
        h2 a0 = {0, 0}, a1 = {0, 0}, a2 = {0, 0}, a3 = {0, 0};
#pragma unroll
        for (int i = 0; i < 64; i += 4) {
            a0 = __builtin_elementwise_fma(bcast(qb, i + 0), Wpk[i + 0], a0);
            a1 = __builtin_elementwise_fma(bcast(qb, i + 1), Wpk[i + 1], a1);
            a2 = __builtin_elementwise_fma(bcast(qb, i + 2), Wpk[i + 2], a2);
            a3 = __builtin_elementwise_fma(bcast(qb, i + 3), Wpk[i + 3], a3);
        }
        h2 s2 = (a0 + a1) + (a2 + a3);
        float ssA = (float)s2[0];
        float ssB = (float)s2[1];
        // per-chain power-of-2 renorm anchored on lane 0 (W-mix bounds spread to 1.56x)
        unsigned int bA = __builtin_amdgcn_readfirstlane(__float_as_uint(ssA));
        int eA = (int)((bA >> 23) & 0xFF); ciA += eA - 127;
        float scA = __uint_as_float((unsigned int)(254 - eA) << 23);
        unsigned int bB = __builtin_amdgcn_readfirstlane(__float_as_uint(ssB));
        int eB = (int)((bB >> 23) & 0xFF); ciB += eB - 127;
        float scB = __uint_as_float((unsigned int)(254 - eB) << 23);
        ppk = pk(ssA * scA * exA, ssB * scB * exB);
    };

    // slot u: fwd x = x_{1+u} (u=0..510; u=511 -> x=0, plain extra W^T mix)
    //         bwd x = x_{1022-u} (u=0..510; slot 511 unused for bwd)
    auto xldA = [&](int u) {
        int uu = u < 510 ? u : 510;
        float v = eb[(size_t)(1 + uu) * T + j];
        return u < 511 ? v : 0.0f;
    };
    auto xldB = [&](int u) {
        int uu = u < 510 ? u : 510;
        return eb[(size_t)(1022 - uu) * T + j];
    };

    // ---- 512 slots, 8-deep ping-pong prefetch for both halves ----
    float xaA[8], xbA[8], xaB[8], xbB[8];
#pragma unroll
    for (int u = 0; u < 8; ++u) { xaA[u] = xldA(u); xaB[u] = xldB(u); }
    int u0 = 0;
    for (int k = 0; k < 31; ++k) {                  // slots 0..495
#pragma unroll
        for (int v = 0; v < 8; ++v) { xbA[v] = xldA(u0 + 8 + v); xbB[v] = xldB(u0 + 8 + v); }
#pragma unroll
        for (int v = 0; v < 8; ++v) dstep(xaA[v], xaB[v]);
#pragma unroll
        for (int v = 0; v < 8; ++v) { xaA[v] = xldA(u0 + 16 + v); xaB[v] = xldB(u0 + 16 + v); }
#pragma unroll
        for (int v = 0; v < 8; ++v) dstep(xbA[v], xbB[v]);
        u0 += 16;
    }
    // u0 = 496; xa* hold slots 496..503
#pragma unroll
    for (int v = 0; v < 8; ++v) { xbA[v] = xldA(504 + v); xbB[v] = xldB(504 + v); }
#pragma unroll
    for (int v = 0; v < 8; ++v) dstep(xaA[v], xaB[v]);   // slots 496..503
#pragma unroll
    for (int v = 0; v < 7; ++v) dstep(xbA[v], xbB[v]);   // slots 504..510
    // bwd complete: save u_512 before the fwd-only extra slot
    float pBf = (float)ppk[1];
    float CB  = cfB + (float)ciB;
    dstep(xbA[7], 0.0f);                                  // slot 511: xA = 0
    float pAf = (float)ppk[0];
    float CA  = cfA + (float)ciA;

    // ---- combine: free = ln2 * (log2(sum_j pAf_j * pBf_j) + CA + CB) ----
    float v = pAf * pBf;
#pragma unroll
    for (int m = 1; m < 64; m <<= 1) v += __shfl_xor(v, m, 64);
    if (j == 0) {
        float free_e = LN2 * (__builtin_amdgcn_logf(v) + CA + CB);
        nll[chain] = free_e - pe;
    }
}

__global__ __launch_bounds__(256, 1) void crf_reduce(const float* __restrict__ nll,
                                                     float* __restrict__ out) {
    float v = nll[threadIdx.x];
#pragma unroll
    for (int m = 1; m < 64; m <<= 1) v += __shfl_xor(v, m, 64);
    __shared__ float acc[4];
    if ((threadIdx.x & 63) == 0) acc[threadIdx.x >> 6] = v;
    __syncthreads();
    if (threadIdx.x == 0) out[0] = (acc[0] + acc[1] + acc[2] + acc[3]) * (1.0f / B);
}

extern "C" void kernel_launch(void* const* d_in, const int* in_sizes, int n_in,
                              void* d_out, int out_size, void* d_ws, size_t ws_size,
                              hipStream_t stream) {
    const float* emis = (const float*)d_in[0];
    const int*   tags = (const int*)d_in[1];
    const float* U    = (const float*)d_in[2];
    const float* bs   = (const float*)d_in[3];
    const float* be   = (const float*)d_in[4];
    float* nll = (float*)d_ws;

    crf_pair<<<dim3(B), dim3(64), 0, stream>>>(emis, tags, U, bs, be, nll);
    crf_reduce<<<dim3(1), dim3(256), 0, stream>>>(nll, (float*)d_out);
}